// Round 1
// baseline (383.272 us; speedup 1.0000x reference)
//
#include <hip/hip_runtime.h>
#include <hip/hip_bf16.h>

#define NH 8
#define HD 64
#define CH 512
#define NT 1024
#define NB 8

typedef __bf16 bf16_t;
typedef bf16_t bf16x8 __attribute__((ext_vector_type(8)));
typedef bf16_t bf16x4 __attribute__((ext_vector_type(4)));
typedef float  f32x4  __attribute__((ext_vector_type(4)));

#define MFMA16(a, b, c) __builtin_amdgcn_mfma_f32_16x16x32_bf16((a), (b), (c), 0, 0, 0)

// ---------------------------------------------------------------------------
// Generic 128x128 GEMM tile:  OUT[n][co] = scale * sum_ci A[n][ci] * W[co][ci]
//   XA=true : A given as fp32 [ci][n], ld=1024 (f_* inputs) -> transpose-stage
//   XA=false: A given as bf16 [n][ci], ld=512  (attn output) -> direct-stage
//   W: fp32 [co][ci], ld=512.  OUT: [n][co], ld=512, type OutT (bf16 or float)
// 256 threads = 4 waves in 2x2; wave tile 64x64 = 4x4 MFMA 16x16x32 frags.
// LDS row stride 40 bf16 = 80B (16B aligned for ds_read_b128, 2-way-conflict).
// ---------------------------------------------------------------------------
template <bool XA, typename OutT>
__device__ __forceinline__ void gemm_body(const void* __restrict__ Asrc,
                                          const float* __restrict__ W,
                                          OutT* __restrict__ Out,
                                          float scale, int n0, int co0,
                                          bf16_t* aT, bf16_t* bT)
{
    constexpr int LDT = 40;
    const int t    = threadIdx.x;
    const int lane = t & 63, wv = t >> 6;
    const int lid  = lane & 15, quad = lane >> 4;
    const int wm   = wv >> 1, wn = wv & 1;

    f32x4 acc[4][4] = {};

    for (int kt = 0; kt < 16; ++kt) {
        const int k0 = kt * 32;
        __syncthreads();
        if constexpr (XA) {
            const float* X = (const float*)Asrc;   // [512][1024]
#pragma unroll
            for (int r = 0; r < 4; ++r) {
                int gid = t + r * 256;             // 1024 float4 chunks
                int ci  = gid >> 5;                // 0..31
                int n4  = gid & 31;                // float4 index along n
                float4 v = *(const float4*)(X + (size_t)(k0 + ci) * NT + n0 + n4 * 4);
                aT[(n4 * 4 + 0) * LDT + ci] = (bf16_t)v.x;
                aT[(n4 * 4 + 1) * LDT + ci] = (bf16_t)v.y;
                aT[(n4 * 4 + 2) * LDT + ci] = (bf16_t)v.z;
                aT[(n4 * 4 + 3) * LDT + ci] = (bf16_t)v.w;
            }
        } else {
            const bf16_t* X = (const bf16_t*)Asrc; // [1024][512]
#pragma unroll
            for (int r = 0; r < 2; ++r) {
                int gid = t + r * 256;             // 512 chunks of 8 bf16
                int row = gid >> 2;
                int cg  = (gid & 3) * 8;
                bf16x8 v = *(const bf16x8*)(X + (size_t)(n0 + row) * CH + k0 + cg);
                *(bf16x8*)(aT + row * LDT + cg) = v;
            }
        }
        // B staging: W[co][ci] fp32 -> bf16 LDS, same layout
#pragma unroll
        for (int r = 0; r < 4; ++r) {
            int gid = t + r * 256;                 // 1024 float4 chunks
            int co  = gid >> 3;                    // 0..127
            int cg  = (gid & 7) * 4;               // 0..28
            float4 v = *(const float4*)(W + (size_t)(co0 + co) * CH + k0 + cg);
            bf16x4 tv = { (bf16_t)v.x, (bf16_t)v.y, (bf16_t)v.z, (bf16_t)v.w };
            *(bf16x4*)(bT + co * LDT + cg) = tv;
        }
        __syncthreads();

        bf16x8 af[4], bfr[4];
#pragma unroll
        for (int i = 0; i < 4; ++i)
            af[i] = *(const bf16x8*)(aT + (wm * 64 + i * 16 + lid) * LDT + quad * 8);
#pragma unroll
        for (int i = 0; i < 4; ++i)
            bfr[i] = *(const bf16x8*)(bT + (wn * 64 + i * 16 + lid) * LDT + quad * 8);
#pragma unroll
        for (int mi = 0; mi < 4; ++mi)
#pragma unroll
            for (int ni = 0; ni < 4; ++ni)
                acc[mi][ni] = MFMA16(af[mi], bfr[ni], acc[mi][ni]);
    }

    // epilogue: D row = quad*4+r (verified m89/m91), col = lid
#pragma unroll
    for (int mi = 0; mi < 4; ++mi)
#pragma unroll
        for (int ni = 0; ni < 4; ++ni)
#pragma unroll
            for (int r = 0; r < 4; ++r) {
                int n  = n0 + wm * 64 + mi * 16 + quad * 4 + r;
                int co = co0 + wn * 64 + ni * 16 + lid;
                Out[(size_t)n * CH + co] = (OutT)(acc[mi][ni][r] * scale);
            }
}

// ---------------------------------------------------------------------------
// Kernel 1: QKV projections.  grid (32 tiles, 8 batches, 5 jobs)
// Q pre-scaled by hd^-0.5 = 0.125 (exact power-of-2 in bf16).
// ---------------------------------------------------------------------------
__global__ __launch_bounds__(256) void qkv_kernel(
    const float* __restrict__ fc, const float* __restrict__ fp,
    const float* __restrict__ fn, const float* __restrict__ Wq,
    const float* __restrict__ Wk, const float* __restrict__ Wv,
    bf16_t* __restrict__ Qn, bf16_t* __restrict__ Kn, bf16_t* __restrict__ Vn)
{
    __shared__ bf16_t aT[128 * 40];
    __shared__ bf16_t bT[128 * 40];
    const int tx = blockIdx.x;
    const int n0 = (tx & 7) * 128;
    const int co0 = (tx >> 3) * 128;
    const int b = blockIdx.y, j = blockIdx.z;

    const float* X; const float* W; bf16_t* O; float scale = 1.0f;
    const size_t fb = (size_t)b * CH * NT;
    switch (j) {
        case 0: X = fc + fb; W = Wq; O = Qn + (size_t)b * NT * CH;                      scale = 0.125f; break;
        case 1: X = fp + fb; W = Wk; O = Kn + (size_t)b * 2 * NT * CH;                  break;
        case 2: X = fn + fb; W = Wk; O = Kn + (size_t)b * 2 * NT * CH + (size_t)NT * CH; break;
        case 3: X = fp + fb; W = Wv; O = Vn + (size_t)b * 2 * NT * CH;                  break;
        default:X = fn + fb; W = Wv; O = Vn + (size_t)b * 2 * NT * CH + (size_t)NT * CH; break;
    }
    gemm_body<true, bf16_t>(X, W, O, scale, n0, co0, aT, bT);
}

// ---------------------------------------------------------------------------
// Kernel 2: flash attention.  grid (8 q-tiles of 128, 8 heads, 8 batches)
// block 256 = 4 waves; wave owns 32 q-rows (2 m-frags) x 64 keys per K-tile.
// V staged transposed ([d][key]) so PV B-frags read contiguous; P goes
// through LDS to convert C/D layout -> A layout (m120 pattern).
// ---------------------------------------------------------------------------
__global__ __launch_bounds__(256) void attn_kernel(
    const bf16_t* __restrict__ Qn, const bf16_t* __restrict__ Kn,
    const bf16_t* __restrict__ Vn, bf16_t* __restrict__ AOn)
{
    constexpr int LDA = 72;                 // 144B rows: 16B aligned, 2-way banks
    __shared__ bf16_t q_lds[128 * LDA];
    __shared__ bf16_t k_lds[64 * LDA];
    __shared__ bf16_t v_lds[64 * LDA];      // transposed: [d][key]
    __shared__ bf16_t p_lds[128 * LDA];

    const int q0 = blockIdx.x * 128;
    const int h = blockIdx.y, b = blockIdx.z;
    const int t = threadIdx.x, wv = t >> 6, lane = t & 63;
    const int lid = lane & 15, quad = lane >> 4;

    const bf16_t* Qb = Qn + (size_t)b * NT * CH + h * HD;
    const bf16_t* Kb = Kn + (size_t)b * 2 * NT * CH + h * HD;
    const bf16_t* Vb = Vn + (size_t)b * 2 * NT * CH + h * HD;

    // stage Q tile [128][64]
#pragma unroll
    for (int r = 0; r < 4; ++r) {
        int gid = t + r * 256;
        int row = gid >> 3, c8 = (gid & 7) * 8;
        *(bf16x8*)(q_lds + row * LDA + c8) =
            *(const bf16x8*)(Qb + (size_t)(q0 + row) * CH + c8);
    }

    f32x4 o[2][4] = {};
    float m_s[2][4], l_s[2][4];
#pragma unroll
    for (int mi = 0; mi < 2; ++mi)
#pragma unroll
        for (int r = 0; r < 4; ++r) { m_s[mi][r] = -__builtin_inff(); l_s[mi][r] = 0.f; }

    for (int kt = 0; kt < 32; ++kt) {
        __syncthreads();
        const int kbase = kt * 64;
#pragma unroll
        for (int r = 0; r < 2; ++r) {
            int gid = t + r * 256;
            int row = gid >> 3, c8 = (gid & 7) * 8;
            *(bf16x8*)(k_lds + row * LDA + c8) =
                *(const bf16x8*)(Kb + (size_t)(kbase + row) * CH + c8);
            bf16x8 vvec = *(const bf16x8*)(Vb + (size_t)(kbase + row) * CH + c8);
#pragma unroll
            for (int u = 0; u < 8; ++u) v_lds[(c8 + u) * LDA + row] = vvec[u];
        }
        __syncthreads();

        // S = Q K^T  (Q pre-scaled)
        f32x4 s[2][4] = {};
#pragma unroll
        for (int ks = 0; ks < 2; ++ks) {
            bf16x8 a0 = *(const bf16x8*)(q_lds + (wv * 32 + lid) * LDA + ks * 32 + quad * 8);
            bf16x8 a1 = *(const bf16x8*)(q_lds + (wv * 32 + 16 + lid) * LDA + ks * 32 + quad * 8);
#pragma unroll
            for (int ni = 0; ni < 4; ++ni) {
                bf16x8 bb = *(const bf16x8*)(k_lds + (ni * 16 + lid) * LDA + ks * 32 + quad * 8);
                s[0][ni] = MFMA16(a0, bb, s[0][ni]);
                s[1][ni] = MFMA16(a1, bb, s[1][ni]);
            }
        }

        // online softmax per owned row (row = mi*16 + quad*4 + r)
#pragma unroll
        for (int mi = 0; mi < 2; ++mi) {
#pragma unroll
            for (int r = 0; r < 4; ++r) {
                float v = fmaxf(fmaxf(s[mi][0][r], s[mi][1][r]),
                                fmaxf(s[mi][2][r], s[mi][3][r]));
                v = fmaxf(v, __shfl_xor(v, 1, 16));
                v = fmaxf(v, __shfl_xor(v, 2, 16));
                v = fmaxf(v, __shfl_xor(v, 4, 16));
                v = fmaxf(v, __shfl_xor(v, 8, 16));
                float mnew  = fmaxf(m_s[mi][r], v);
                float alpha = __expf(m_s[mi][r] - mnew);
                m_s[mi][r] = mnew;
                float rs = 0.f;
#pragma unroll
                for (int ni = 0; ni < 4; ++ni) {
                    float p = __expf(s[mi][ni][r] - mnew);
                    s[mi][ni][r] = p;
                    rs += p;
                }
                rs += __shfl_xor(rs, 1, 16);
                rs += __shfl_xor(rs, 2, 16);
                rs += __shfl_xor(rs, 4, 16);
                rs += __shfl_xor(rs, 8, 16);
                l_s[mi][r] = l_s[mi][r] * alpha + rs;
#pragma unroll
                for (int ni = 0; ni < 4; ++ni) o[mi][ni][r] *= alpha;
#pragma unroll
                for (int ni = 0; ni < 4; ++ni)
                    p_lds[(wv * 32 + mi * 16 + quad * 4 + r) * LDA + ni * 16 + lid] =
                        (bf16_t)s[mi][ni][r];
            }
        }

        // O += P V   (p_lds write->read within same wave: lgkmcnt handled)
#pragma unroll
        for (int ks = 0; ks < 2; ++ks) {
            bf16x8 a0 = *(const bf16x8*)(p_lds + (wv * 32 + lid) * LDA + ks * 32 + quad * 8);
            bf16x8 a1 = *(const bf16x8*)(p_lds + (wv * 32 + 16 + lid) * LDA + ks * 32 + quad * 8);
#pragma unroll
            for (int ni = 0; ni < 4; ++ni) {
                bf16x8 bb = *(const bf16x8*)(v_lds + (ni * 16 + lid) * LDA + ks * 32 + quad * 8);
                o[0][ni] = MFMA16(a0, bb, o[0][ni]);
                o[1][ni] = MFMA16(a1, bb, o[1][ni]);
            }
        }
    }

    bf16_t* Ob = AOn + (size_t)b * NT * CH + h * HD;
#pragma unroll
    for (int mi = 0; mi < 2; ++mi)
#pragma unroll
        for (int ni = 0; ni < 4; ++ni)
#pragma unroll
            for (int r = 0; r < 4; ++r) {
                int row = q0 + wv * 32 + mi * 16 + quad * 4 + r;
                int d   = ni * 16 + lid;
                Ob[(size_t)row * CH + d] = (bf16_t)(o[mi][ni][r] / l_s[mi][r]);
            }
}

// ---------------------------------------------------------------------------
// Kernel 3: output projection Y = AO @ Wo^T (fp32 out). grid (32, 8)
// ---------------------------------------------------------------------------
__global__ __launch_bounds__(256) void proj_kernel(
    const bf16_t* __restrict__ AOn, const float* __restrict__ Wo,
    float* __restrict__ Y)
{
    __shared__ bf16_t aT[128 * 40];
    __shared__ bf16_t bT[128 * 40];
    const int tx = blockIdx.x;
    const int n0 = (tx & 7) * 128;
    const int co0 = (tx >> 3) * 128;
    const int b = blockIdx.y;
    gemm_body<false, float>(AOn + (size_t)b * NT * CH, Wo,
                            Y + (size_t)b * NT * CH, 1.0f, n0, co0, aT, bT);
}

// ---------------------------------------------------------------------------
// Kernel 4: residual + LayerNorm + transpose to [B,C,H,W]. grid (16, 8)
// z[n][co] = Y[b,n,co] + f_curr[b,co,n]; LN over co; out[b,co,n].
// ---------------------------------------------------------------------------
__global__ __launch_bounds__(256) void ln_kernel(
    const float* __restrict__ Y, const float* __restrict__ fcur,
    const float* __restrict__ gamma, const float* __restrict__ beta,
    float* __restrict__ out)
{
    __shared__ float part[64 * 4 * 2];
    __shared__ float mu_s[64], rs_s[64];
    const int b = blockIdx.y;
    const int n0 = blockIdx.x * 64;
    const int t = threadIdx.x;
    const float* Yb = Y + (size_t)b * NT * CH;
    const float* fb = fcur + (size_t)b * CH * NT;

    // pass 1: stats (4 threads per row)
    {
        int row = t >> 2, pid = t & 3;
        const float* Yr = Yb + (size_t)(n0 + row) * CH;
        const float* fr = fb + n0 + row;
        float sum = 0.f, sq = 0.f;
#pragma unroll 4
        for (int k = 0; k < 32; ++k) {
            int co = (pid + k * 4) * 4;
            float4 y = *(const float4*)(Yr + co);
            float z0 = y.x + fr[(size_t)(co + 0) * NT];
            float z1 = y.y + fr[(size_t)(co + 1) * NT];
            float z2 = y.z + fr[(size_t)(co + 2) * NT];
            float z3 = y.w + fr[(size_t)(co + 3) * NT];
            sum += z0 + z1 + z2 + z3;
            sq  += z0 * z0 + z1 * z1 + z2 * z2 + z3 * z3;
        }
        part[(row * 4 + pid) * 2 + 0] = sum;
        part[(row * 4 + pid) * 2 + 1] = sq;
    }
    __syncthreads();
    if (t < 64) {
        float s = 0.f, q = 0.f;
#pragma unroll
        for (int i = 0; i < 4; ++i) {
            s += part[(t * 4 + i) * 2 + 0];
            q += part[(t * 4 + i) * 2 + 1];
        }
        float mu  = s * (1.0f / 512.0f);
        float var = q * (1.0f / 512.0f) - mu * mu;
        mu_s[t] = mu;
        rs_s[t] = rsqrtf(var + 1e-5f);
    }
    __syncthreads();

    // pass 2: normalize, coalesced transposed writes (64 lanes along n)
    {
        int n = t & 63, g = t >> 6;
        float* ob = out + (size_t)b * CH * NT + n0 + n;
        float mu = mu_s[n], rs = rs_s[n];
#pragma unroll 4
        for (int k = 0; k < 128; ++k) {
            int co = k * 4 + g;
            float z = Yb[(size_t)(n0 + n) * CH + co] + fb[(size_t)co * NT + n0 + n];
            ob[(size_t)co * NT] = (z - mu) * rs * gamma[co] + beta[co];
        }
    }
}

// ---------------------------------------------------------------------------
extern "C" void kernel_launch(void* const* d_in, const int* in_sizes, int n_in,
                              void* d_out, int out_size, void* d_ws, size_t ws_size,
                              hipStream_t stream)
{
    (void)in_sizes; (void)n_in; (void)out_size; (void)ws_size;
    const float* fc    = (const float*)d_in[0];
    const float* fp    = (const float*)d_in[1];
    const float* fn    = (const float*)d_in[2];
    const float* Wq    = (const float*)d_in[3];
    const float* Wk    = (const float*)d_in[4];
    const float* Wv    = (const float*)d_in[5];
    const float* Wo    = (const float*)d_in[6];
    const float* gamma = (const float*)d_in[7];
    const float* beta  = (const float*)d_in[8];
    float* out = (float*)d_out;

    char* ws = (char*)d_ws;
    // layout (48 MB total): Qn 8MB | Kn 16MB | Vn 16MB | AOn 8MB ; Y reuses [0,16MB)
    bf16_t* Qn  = (bf16_t*)(ws);
    bf16_t* Kn  = (bf16_t*)(ws + 8388608);
    bf16_t* Vn  = (bf16_t*)(ws + 25165824);
    bf16_t* AOn = (bf16_t*)(ws + 41943040);
    float*  Y   = (float*)(ws);   // safe: proj runs after attn has consumed Qn/Kn

    qkv_kernel<<<dim3(32, 8, 5), 256, 0, stream>>>(fc, fp, fn, Wq, Wk, Wv, Qn, Kn, Vn);
    attn_kernel<<<dim3(8, 8, 8), 256, 0, stream>>>(Qn, Kn, Vn, AOn);
    proj_kernel<<<dim3(32, 8, 1), 256, 0, stream>>>(AOn, Wo, Y);
    ln_kernel<<<dim3(16, 8, 1), 256, 0, stream>>>(Y, fc, gamma, beta, out);
}

// Round 2
// 330.340 us; speedup vs baseline: 1.1602x; 1.1602x over previous
//
#include <hip/hip_runtime.h>
#include <hip/hip_bf16.h>
#include <math.h>

#define NH 8
#define HD 64
#define CH 512
#define NT 1024
#define NB 8

typedef __bf16 bf16_t;
typedef bf16_t bf16x8 __attribute__((ext_vector_type(8)));
typedef bf16_t bf16x4 __attribute__((ext_vector_type(4)));
typedef float  f32x4  __attribute__((ext_vector_type(4)));
typedef float  f32x16 __attribute__((ext_vector_type(16)));

#define MFMA16(a, b, c) __builtin_amdgcn_mfma_f32_16x16x32_bf16((a), (b), (c), 0, 0, 0)
#define MFMA32(a, b, c) __builtin_amdgcn_mfma_f32_32x32x16_bf16((a), (b), (c), 0, 0, 0)

// ---------------------------------------------------------------------------
// 128x128 GEMM tile, 16x16x32 MFMA.
// MODE 0: A = fp32 [ci][n] (transpose-stage), out[n][co] (Q/K jobs)
// MODE 1: A = bf16 [n][ci] (direct-stage),    out[n][co] (proj)
// MODE 2: A = fp32 [ci][n] (transpose-stage), out = Vt[co][key] (V jobs,
//         operand swap: m-side = co from W, n-side = key) - coalesced Vt write
// ---------------------------------------------------------------------------
template <int MODE, typename OutT>
__device__ __forceinline__ void gemm_body(const void* __restrict__ Asrc,
                                          const float* __restrict__ W,
                                          OutT* __restrict__ Out,
                                          float scale, int n0, int co0,
                                          bf16_t* aT, bf16_t* bT)
{
    constexpr int LDT = 40;
    const int t    = threadIdx.x;
    const int lane = t & 63, wv = t >> 6;
    const int lid  = lane & 15, quad = lane >> 4;
    const int wm   = wv >> 1, wn = wv & 1;

    f32x4 acc[4][4] = {};

    for (int kt = 0; kt < 16; ++kt) {
        const int k0 = kt * 32;
        __syncthreads();
        if constexpr (MODE != 1) {
            const float* X = (const float*)Asrc;   // [512][1024]
#pragma unroll
            for (int r = 0; r < 4; ++r) {
                int gid = t + r * 256;             // 1024 float4 chunks
                int ci  = gid >> 5;                // 0..31
                int n4  = gid & 31;                // float4 index along n
                float4 v = *(const float4*)(X + (size_t)(k0 + ci) * NT + n0 + n4 * 4);
                aT[(n4 * 4 + 0) * LDT + ci] = (bf16_t)v.x;
                aT[(n4 * 4 + 1) * LDT + ci] = (bf16_t)v.y;
                aT[(n4 * 4 + 2) * LDT + ci] = (bf16_t)v.z;
                aT[(n4 * 4 + 3) * LDT + ci] = (bf16_t)v.w;
            }
        } else {
            const bf16_t* X = (const bf16_t*)Asrc; // [1024][512]
#pragma unroll
            for (int r = 0; r < 2; ++r) {
                int gid = t + r * 256;
                int row = gid >> 2;
                int cg  = (gid & 3) * 8;
                bf16x8 v = *(const bf16x8*)(X + (size_t)(n0 + row) * CH + k0 + cg);
                *(bf16x8*)(aT + row * LDT + cg) = v;
            }
        }
#pragma unroll
        for (int r = 0; r < 4; ++r) {
            int gid = t + r * 256;
            int co  = gid >> 3;
            int cg  = (gid & 7) * 4;
            float4 v = *(const float4*)(W + (size_t)(co0 + co) * CH + k0 + cg);
            bf16x4 tv = { (bf16_t)v.x, (bf16_t)v.y, (bf16_t)v.z, (bf16_t)v.w };
            *(bf16x4*)(bT + co * LDT + cg) = tv;
        }
        __syncthreads();

        // MODE 2: swap operand roles (m-side = W rows, n-side = X^T rows)
        const bf16_t* aF = (MODE == 2) ? bT : aT;
        const bf16_t* bF = (MODE == 2) ? aT : bT;

        bf16x8 af[4], bfr[4];
#pragma unroll
        for (int i = 0; i < 4; ++i)
            af[i] = *(const bf16x8*)(aF + (wm * 64 + i * 16 + lid) * LDT + quad * 8);
#pragma unroll
        for (int i = 0; i < 4; ++i)
            bfr[i] = *(const bf16x8*)(bF + (wn * 64 + i * 16 + lid) * LDT + quad * 8);
#pragma unroll
        for (int mi = 0; mi < 4; ++mi)
#pragma unroll
            for (int ni = 0; ni < 4; ++ni)
                acc[mi][ni] = MFMA16(af[mi], bfr[ni], acc[mi][ni]);
    }

    if constexpr (MODE != 2) {
#pragma unroll
        for (int mi = 0; mi < 4; ++mi)
#pragma unroll
            for (int ni = 0; ni < 4; ++ni)
#pragma unroll
                for (int r = 0; r < 4; ++r) {
                    int n  = n0 + wm * 64 + mi * 16 + quad * 4 + r;
                    int co = co0 + wn * 64 + ni * 16 + lid;
                    Out[(size_t)n * CH + co] = (OutT)(acc[mi][ni][r] * scale);
                }
    } else {
        // Vt[co][key], key-contiguous (32B segments per quad-row)
#pragma unroll
        for (int mi = 0; mi < 4; ++mi)
#pragma unroll
            for (int ni = 0; ni < 4; ++ni)
#pragma unroll
                for (int r = 0; r < 4; ++r) {
                    int co_l  = wm * 64 + mi * 16 + quad * 4 + r;
                    int key_l = wn * 64 + ni * 16 + lid;
                    Out[(size_t)(co0 + co_l) * (2 * NT) + n0 + key_l] =
                        (OutT)(acc[mi][ni][r]);
                }
    }
}

// ---------------------------------------------------------------------------
// Kernel 1: QKV projections.  grid (32 tiles, 8 batches, 5 jobs)
// Q pre-scaled by hd^-0.5 * log2(e) so attention uses exp2.
// V jobs write transposed Vt[b][c][2N].
// ---------------------------------------------------------------------------
__global__ __launch_bounds__(256) void qkv_kernel(
    const float* __restrict__ fc, const float* __restrict__ fp,
    const float* __restrict__ fn, const float* __restrict__ Wq,
    const float* __restrict__ Wk, const float* __restrict__ Wv,
    bf16_t* __restrict__ Qn, bf16_t* __restrict__ Kn, bf16_t* __restrict__ Vt)
{
    __shared__ __align__(16) bf16_t aT[128 * 40];
    __shared__ __align__(16) bf16_t bT[128 * 40];
    const int tx = blockIdx.x;
    const int n0 = (tx & 7) * 128;
    const int co0 = (tx >> 3) * 128;
    const int b = blockIdx.y, j = blockIdx.z;
    const size_t fb = (size_t)b * CH * NT;
    const float QSC = 0.125f * 1.44269504f;

    switch (j) {
        case 0: gemm_body<0, bf16_t>(fc + fb, Wq, Qn + (size_t)b * NT * CH, QSC, n0, co0, aT, bT); break;
        case 1: gemm_body<0, bf16_t>(fp + fb, Wk, Kn + (size_t)b * 2 * NT * CH, 1.0f, n0, co0, aT, bT); break;
        case 2: gemm_body<0, bf16_t>(fn + fb, Wk, Kn + (size_t)b * 2 * NT * CH + (size_t)NT * CH, 1.0f, n0, co0, aT, bT); break;
        case 3: gemm_body<2, bf16_t>(fp + fb, Wv, Vt + (size_t)b * CH * 2 * NT, 1.0f, n0, co0, aT, bT); break;
        default:gemm_body<2, bf16_t>(fn + fb, Wv, Vt + (size_t)b * CH * 2 * NT + NT, 1.0f, n0, co0, aT, bT); break;
    }
}

// ---------------------------------------------------------------------------
// Kernel 2: attention, S^T formulation, 32x32x16 MFMA, no-max softmax.
// grid (8 q-tiles of 128, 8 heads, 8 batches); block 256 = 4 waves (2wq x 2wk)
// wave tile: 64 q x 64 keys; K-tile 128 keys/iter, 16 iters.
// Q register-resident; K/V share one LDS buffer (reg prefetch, 4 barriers/kt)
// XOR-swizzled LDS (col ^= row&24) -> all staging/frag accesses <=2-way.
// ---------------------------------------------------------------------------
__global__ __launch_bounds__(256) void attn_kernel(
    const bf16_t* __restrict__ Qn, const bf16_t* __restrict__ Kn,
    const bf16_t* __restrict__ Vt, bf16_t* __restrict__ AOn)
{
    __shared__ __align__(16) bf16_t kv[128 * 72];     // K [128][72] / V [64][136] / out [128][72]
    __shared__ __align__(16) float  pqf[9216];        // Q-stage [128][72]bf16, then P (4x[64][72]bf16), then O-scratch f32
    __shared__ float l_scr[128];

    bf16_t* pq = (bf16_t*)pqf;

    const int t = threadIdx.x;
    const int w = t >> 6, lane = t & 63;
    const int wq = w >> 1, wk = w & 1;
    const int l31 = lane & 31, h = lane >> 5;

    const int q0 = blockIdx.x * 128;
    const int hh = blockIdx.y, b = blockIdx.z;

    const bf16_t* Qb  = Qn + ((size_t)b * NT + q0) * CH + hh * HD;
    const bf16_t* Kb  = Kn + (size_t)b * 2 * NT * CH + hh * HD;
    const bf16_t* Vtb = Vt + ((size_t)b * CH + hh * HD) * (2 * NT);
    bf16_t* AOb = AOn + ((size_t)b * NT + q0) * CH + hh * HD;

    // ---- stage Q tile [128 q][64 d] (swizzled) ----
#pragma unroll
    for (int i = 0; i < 4; ++i) {
        int gid = t + i * 256;
        int qr = gid >> 3, c8 = (gid & 7) * 8;
        *(bf16x8*)(pq + qr * 72 + (c8 ^ (qr & 24))) =
            *(const bf16x8*)(Qb + (size_t)qr * CH + c8);
    }
    __syncthreads();

    // prefetch K(0)
    bf16x8 kreg[4];
#pragma unroll
    for (int i = 0; i < 4; ++i) {
        int gid = t + i * 256;
        int kr = gid >> 3, c8 = (gid & 7) * 8;
        kreg[i] = *(const bf16x8*)(Kb + (size_t)kr * CH + c8);
    }

    // Q B-frags -> registers: B[k=d][n=q], lane: q = base+l31, d = ks*16+h*8+j
    bf16x8 qf[2][4];
#pragma unroll
    for (int nf = 0; nf < 2; ++nf)
#pragma unroll
        for (int ks = 0; ks < 4; ++ks) {
            int row = wq * 64 + nf * 32 + l31;
            int col = (ks * 16 + h * 8) ^ (row & 24);
            qf[nf][ks] = *(const bf16x8*)(pq + row * 72 + col);
        }
    __syncthreads();   // Q-frag reads done; pq becomes P space

    bf16_t* pw = pq + w * 4608;   // per-wave P [64 q][72 keys]

    f32x16 o[2][2] = {};          // O^T [df][nf]
    float lpart[2] = {0.f, 0.f};

    for (int kt = 0; kt < 16; ++kt) {
        const int kbase = kt * 128;

        // write K(kt) -> kv [128 keys][72]
#pragma unroll
        for (int i = 0; i < 4; ++i) {
            int gid = t + i * 256;
            int kr = gid >> 3, c8 = (gid & 7) * 8;
            *(bf16x8*)(kv + kr * 72 + (c8 ^ (kr & 24))) = kreg[i];
        }
        __syncthreads();

        // prefetch V(kt): Vt rows d, [64 d][128 keys]
        bf16x8 vreg[4];
#pragma unroll
        for (int i = 0; i < 4; ++i) {
            int gid = t + i * 256;
            int dr = gid >> 4, c8 = (gid & 15) * 8;
            vreg[i] = *(const bf16x8*)(Vtb + (size_t)dr * (2 * NT) + kbase + c8);
        }

        // ---- S^T = K * Q^T ----
        f32x16 s[2][2] = {};
#pragma unroll
        for (int ks = 0; ks < 4; ++ks) {
            bf16x8 af[2];
#pragma unroll
            for (int mf = 0; mf < 2; ++mf) {
                int arow = wk * 64 + mf * 32 + l31;
                int acol = (ks * 16 + h * 8) ^ (arow & 24);
                af[mf] = *(const bf16x8*)(kv + arow * 72 + acol);
            }
#pragma unroll
            for (int mf = 0; mf < 2; ++mf)
#pragma unroll
                for (int nf = 0; nf < 2; ++nf)
                    s[mf][nf] = MFMA32(af[mf], qf[nf][ks], s[mf][nf]);
        }

        // ---- exp2, l accumulation, P^T -> LDS (b64 packed) ----
#pragma unroll
        for (int mf = 0; mf < 2; ++mf)
#pragma unroll
            for (int nf = 0; nf < 2; ++nf) {
                int qrow = nf * 32 + l31;
#pragma unroll
                for (int g = 0; g < 4; ++g) {
                    float p0 = exp2f(s[mf][nf][4 * g + 0]);
                    float p1 = exp2f(s[mf][nf][4 * g + 1]);
                    float p2 = exp2f(s[mf][nf][4 * g + 2]);
                    float p3 = exp2f(s[mf][nf][4 * g + 3]);
                    lpart[nf] += (p0 + p1) + (p2 + p3);
                    bf16x4 pk = { (bf16_t)p0, (bf16_t)p1, (bf16_t)p2, (bf16_t)p3 };
                    int kb = mf * 32 + 8 * g + 4 * h;     // wave-local key
                    *(bf16x4*)(pw + qrow * 72 + (kb ^ (qrow & 24))) = pk;
                }
            }
        __syncthreads();   // all waves done reading K

        // write V(kt) -> kv as [64 d][136 keys]
#pragma unroll
        for (int i = 0; i < 4; ++i) {
            int gid = t + i * 256;
            int dr = gid >> 4, c8 = (gid & 15) * 8;
            *(bf16x8*)(kv + dr * 136 + (c8 ^ (dr & 24))) = vreg[i];
        }
        __syncthreads();

        // prefetch K(kt+1)
        const int nb = (kt < 15) ? kbase + 128 : kbase;
#pragma unroll
        for (int i = 0; i < 4; ++i) {
            int gid = t + i * 256;
            int kr = gid >> 3, c8 = (gid & 7) * 8;
            kreg[i] = *(const bf16x8*)(Kb + (size_t)(nb + kr) * CH + c8);
        }

        // ---- O^T += V^T * P^T ----
#pragma unroll
        for (int ks = 0; ks < 4; ++ks) {
            bf16x8 av[2], bp[2];
#pragma unroll
            for (int df = 0; df < 2; ++df) {
                int vrow = df * 32 + l31;
                int vcol = (wk * 64 + ks * 16 + h * 8) ^ (vrow & 24);
                av[df] = *(const bf16x8*)(kv + vrow * 136 + vcol);
            }
#pragma unroll
            for (int nf = 0; nf < 2; ++nf) {
                int bq = nf * 32 + l31;
                int bcol = (ks * 16 + h * 8) ^ (bq & 24);
                bp[nf] = *(const bf16x8*)(pw + bq * 72 + bcol);
            }
#pragma unroll
            for (int df = 0; df < 2; ++df)
#pragma unroll
                for (int nf = 0; nf < 2; ++nf)
                    o[df][nf] = MFMA32(av[df], bp[nf], o[df][nf]);
        }
        __syncthreads();   // PV reads done before next K overwrite
    }

    // ---- combine across wk, divide by l, write out ----
    float l2[2];
#pragma unroll
    for (int nf = 0; nf < 2; ++nf)
        l2[nf] = lpart[nf] + __shfl_xor(lpart[nf], 32);

    if (wk == 1) {
        float* scr = pqf + wq * 4352;   // [64 q][68 d] f32
#pragma unroll
        for (int df = 0; df < 2; ++df)
#pragma unroll
            for (int nf = 0; nf < 2; ++nf) {
                int qrow = nf * 32 + l31;
#pragma unroll
                for (int g = 0; g < 4; ++g) {
                    int d = df * 32 + 8 * g + 4 * h;
                    f32x4 v = { o[df][nf][4 * g + 0], o[df][nf][4 * g + 1],
                                o[df][nf][4 * g + 2], o[df][nf][4 * g + 3] };
                    *(f32x4*)(scr + qrow * 68 + d) = v;
                }
            }
        if (h == 0) {
            l_scr[wq * 64 + 0 * 32 + l31] = l2[0];
            l_scr[wq * 64 + 1 * 32 + l31] = l2[1];
        }
    }
    __syncthreads();

    if (wk == 0) {
        const float* scr = pqf + wq * 4352;
        float inv[2];
#pragma unroll
        for (int nf = 0; nf < 2; ++nf)
            inv[nf] = 1.0f / (l2[nf] + l_scr[wq * 64 + nf * 32 + l31]);
#pragma unroll
        for (int df = 0; df < 2; ++df)
#pragma unroll
            for (int nf = 0; nf < 2; ++nf) {
                int qrow = nf * 32 + l31;
#pragma unroll
                for (int g = 0; g < 4; ++g) {
                    int d = df * 32 + 8 * g + 4 * h;
                    f32x4 part = *(const f32x4*)(scr + qrow * 68 + d);
                    bf16x4 ov = {
                        (bf16_t)((o[df][nf][4 * g + 0] + part.x) * inv[nf]),
                        (bf16_t)((o[df][nf][4 * g + 1] + part.y) * inv[nf]),
                        (bf16_t)((o[df][nf][4 * g + 2] + part.z) * inv[nf]),
                        (bf16_t)((o[df][nf][4 * g + 3] + part.w) * inv[nf]) };
                    int qg = wq * 64 + qrow;
                    *(bf16x4*)(kv + qg * 72 + (d ^ (qg & 24))) = ov;
                }
            }
    }
    __syncthreads();

    // coalesced readback [128 q][64 d] -> AO
#pragma unroll
    for (int i = 0; i < 4; ++i) {
        int gid = t + i * 256;
        int qr = gid >> 3, c8 = (gid & 7) * 8;
        *(bf16x8*)(AOb + (size_t)qr * CH + c8) =
            *(const bf16x8*)(kv + qr * 72 + (c8 ^ (qr & 24)));
    }
}

// ---------------------------------------------------------------------------
// Kernel 3: output projection Y = AO @ Wo^T (fp32 out). grid (32, 8)
// ---------------------------------------------------------------------------
__global__ __launch_bounds__(256) void proj_kernel(
    const bf16_t* __restrict__ AOn, const float* __restrict__ Wo,
    float* __restrict__ Y)
{
    __shared__ __align__(16) bf16_t aT[128 * 40];
    __shared__ __align__(16) bf16_t bT[128 * 40];
    const int tx = blockIdx.x;
    const int n0 = (tx & 7) * 128;
    const int co0 = (tx >> 3) * 128;
    const int b = blockIdx.y;
    gemm_body<1, float>(AOn + (size_t)b * NT * CH, Wo,
                        Y + (size_t)b * NT * CH, 1.0f, n0, co0, aT, bT);
}

// ---------------------------------------------------------------------------
// Kernel 4: residual + LayerNorm + transpose to [B,C,H,W]. grid (16, 8)
// ---------------------------------------------------------------------------
__global__ __launch_bounds__(256) void ln_kernel(
    const float* __restrict__ Y, const float* __restrict__ fcur,
    const float* __restrict__ gamma, const float* __restrict__ beta,
    float* __restrict__ out)
{
    __shared__ float part[64 * 4 * 2];
    __shared__ float mu_s[64], rs_s[64];
    const int b = blockIdx.y;
    const int n0 = blockIdx.x * 64;
    const int t = threadIdx.x;
    const float* Yb = Y + (size_t)b * NT * CH;
    const float* fb = fcur + (size_t)b * CH * NT;

    {
        int row = t >> 2, pid = t & 3;
        const float* Yr = Yb + (size_t)(n0 + row) * CH;
        const float* fr = fb + n0 + row;
        float sum = 0.f, sq = 0.f;
#pragma unroll 4
        for (int k = 0; k < 32; ++k) {
            int co = (pid + k * 4) * 4;
            float4 y = *(const float4*)(Yr + co);
            float z0 = y.x + fr[(size_t)(co + 0) * NT];
            float z1 = y.y + fr[(size_t)(co + 1) * NT];
            float z2 = y.z + fr[(size_t)(co + 2) * NT];
            float z3 = y.w + fr[(size_t)(co + 3) * NT];
            sum += z0 + z1 + z2 + z3;
            sq  += z0 * z0 + z1 * z1 + z2 * z2 + z3 * z3;
        }
        part[(row * 4 + pid) * 2 + 0] = sum;
        part[(row * 4 + pid) * 2 + 1] = sq;
    }
    __syncthreads();
    if (t < 64) {
        float s = 0.f, q = 0.f;
#pragma unroll
        for (int i = 0; i < 4; ++i) {
            s += part[(t * 4 + i) * 2 + 0];
            q += part[(t * 4 + i) * 2 + 1];
        }
        float mu  = s * (1.0f / 512.0f);
        float var = q * (1.0f / 512.0f) - mu * mu;
        mu_s[t] = mu;
        rs_s[t] = rsqrtf(var + 1e-5f);
    }
    __syncthreads();

    {
        int n = t & 63, g = t >> 6;
        float* ob = out + (size_t)b * CH * NT + n0 + n;
        float mu = mu_s[n], rs = rs_s[n];
#pragma unroll 4
        for (int k = 0; k < 128; ++k) {
            int co = k * 4 + g;
            float z = Yb[(size_t)(n0 + n) * CH + co] + fb[(size_t)co * NT + n0 + n];
            ob[(size_t)co * NT] = (z - mu) * rs * gamma[co] + beta[co];
        }
    }
}

// ---------------------------------------------------------------------------
extern "C" void kernel_launch(void* const* d_in, const int* in_sizes, int n_in,
                              void* d_out, int out_size, void* d_ws, size_t ws_size,
                              hipStream_t stream)
{
    (void)in_sizes; (void)n_in; (void)out_size; (void)ws_size;
    const float* fc    = (const float*)d_in[0];
    const float* fp    = (const float*)d_in[1];
    const float* fn    = (const float*)d_in[2];
    const float* Wq    = (const float*)d_in[3];
    const float* Wk    = (const float*)d_in[4];
    const float* Wv    = (const float*)d_in[5];
    const float* Wo    = (const float*)d_in[6];
    const float* gamma = (const float*)d_in[7];
    const float* beta  = (const float*)d_in[8];
    float* out = (float*)d_out;

    char* ws = (char*)d_ws;
    // layout (48 MB): Qn 8MB | Kn 16MB | Vt 16MB | AOn 8MB ; Y f32 reuses [0,16MB)
    bf16_t* Qn  = (bf16_t*)(ws);
    bf16_t* Kn  = (bf16_t*)(ws + 8388608);
    bf16_t* Vt  = (bf16_t*)(ws + 25165824);
    bf16_t* AOn = (bf16_t*)(ws + 41943040);
    float*  Y   = (float*)(ws);   // safe: proj runs after attn consumed Qn/Kn

    qkv_kernel<<<dim3(32, 8, 5), 256, 0, stream>>>(fc, fp, fn, Wq, Wk, Wv, Qn, Kn, Vt);
    attn_kernel<<<dim3(8, 8, 8), 256, 0, stream>>>(Qn, Kn, Vt, AOn);
    proj_kernel<<<dim3(32, 8, 1), 256, 0, stream>>>(AOn, Wo, Y);
    ln_kernel<<<dim3(16, 8, 1), 256, 0, stream>>>(Y, fc, gamma, beta, out);
}

// Round 3
// 252.946 us; speedup vs baseline: 1.5152x; 1.3060x over previous
//
#include <hip/hip_runtime.h>
#include <hip/hip_bf16.h>
#include <math.h>

#define NH 8
#define HD 64
#define CH 512
#define NT 1024
#define NB 8

typedef __bf16 bf16_t;
typedef bf16_t bf16x8 __attribute__((ext_vector_type(8)));
typedef bf16_t bf16x4 __attribute__((ext_vector_type(4)));
typedef float  f32x4  __attribute__((ext_vector_type(4)));
typedef float  f32x16 __attribute__((ext_vector_type(16)));

#define MFMA16(a, b, c) __builtin_amdgcn_mfma_f32_16x16x32_bf16((a), (b), (c), 0, 0, 0)
#define MFMA32(a, b, c) __builtin_amdgcn_mfma_f32_32x32x16_bf16((a), (b), (c), 0, 0, 0)

__device__ __forceinline__ void gload16(const void* g, void* l) {
    __builtin_amdgcn_global_load_lds(
        (const __attribute__((address_space(1))) void*)g,
        (__attribute__((address_space(3))) void*)l, 16, 0, 0);
}

// ---------------------------------------------------------------------------
// prep: fp32 [C][N] -> bf16 [N][C] transpose (per 64x64 tile).
// grid (128, 24): x = tile (c-tile = x&7, n-tile = x>>3); y: b = y/3, ft = y%3
// Register 4x4 transpose + XOR-swizzled LDS: all global accesses coalesced,
// LDS writes 2-way max, reads conflict-free.
// ---------------------------------------------------------------------------
__global__ __launch_bounds__(256) void prep_kernel(
    const float* __restrict__ fc, const float* __restrict__ fp,
    const float* __restrict__ fn, bf16_t* __restrict__ Xc,
    bf16_t* __restrict__ Xn)
{
    __shared__ __align__(16) bf16_t tile[64 * 64];
    const int t = threadIdx.x;
    const int y = blockIdx.y;
    const int b = y / 3, ft = y % 3;
    const int c0 = (blockIdx.x & 7) * 64;
    const int n0 = (blockIdx.x >> 3) * 64;

    const float* src; bf16_t* dst;
    if (ft == 0)      { src = fc + (size_t)b * CH * NT; dst = Xc + (size_t)b * NT * CH; }
    else if (ft == 1) { src = fp + (size_t)b * CH * NT; dst = Xn + (size_t)b * 2 * NT * CH; }
    else              { src = fn + (size_t)b * CH * NT; dst = Xn + (size_t)b * 2 * NT * CH + (size_t)NT * CH; }

    const int nb = t & 15, cb = t >> 4;   // 4-wide chunks
    float4 ld[4];
#pragma unroll
    for (int i = 0; i < 4; ++i)
        ld[i] = *(const float4*)(src + (size_t)(c0 + cb * 4 + i) * NT + n0 + nb * 4);
    const float* lf = (const float*)ld;
#pragma unroll
    for (int j = 0; j < 4; ++j) {
        int n = nb * 4 + j;
        int v = (n >> 2) & 14;            // even -> bf16x8 readback stays contiguous
        bf16x4 wv = { (bf16_t)lf[0 * 4 + j], (bf16_t)lf[1 * 4 + j],
                      (bf16_t)lf[2 * 4 + j], (bf16_t)lf[3 * 4 + j] };
        *(bf16x4*)(tile + n * 64 + ((cb ^ v) * 4)) = wv;
    }
    __syncthreads();
#pragma unroll
    for (int i = 0; i < 2; ++i) {
        int gid = t + i * 256;            // 512 chunks of 16B
        int n = gid >> 3, c16 = gid & 7;
        int v = (n >> 2) & 14;
        bf16x8 val = *(const bf16x8*)(tile + n * 64 + (((2 * c16) ^ v) * 4));
        *(bf16x8*)(dst + (size_t)(n0 + n) * CH + c0 + c16 * 8) = val;
    }
}

// weights fp32 -> bf16, grid (256, 4)
__global__ __launch_bounds__(256) void wcvt_kernel(
    const float* __restrict__ Wq, const float* __restrict__ Wk,
    const float* __restrict__ Wv, const float* __restrict__ Wo,
    bf16_t* __restrict__ Wb)
{
    const int m = blockIdx.y;
    const float* src = (m == 0) ? Wq : (m == 1) ? Wk : (m == 2) ? Wv : Wo;
    bf16_t* dst = Wb + (size_t)m * CH * CH;
    int gid = blockIdx.x * 256 + threadIdx.x;      // 65536 float4 per matrix
    float4 v = *(const float4*)(src + (size_t)gid * 4);
    bf16x4 o = { (bf16_t)v.x, (bf16_t)v.y, (bf16_t)v.z, (bf16_t)v.w };
    *(bf16x4*)(dst + (size_t)gid * 4) = o;
}

// ---------------------------------------------------------------------------
// gemm_core: 128x128 tile, K=512, BK=32, all-bf16, global_load_lds staging.
// LDS tiles [128][32] unpadded (lds-DMA needs lane-contiguous dest); the
// gptr-side swizzle k4 ^= (row>>1)&3 makes all frag ds_read_b128 conflict-free.
// SWAP=false: m-side = A rows, n-side = B rows.  SWAP=true: swapped.
// ---------------------------------------------------------------------------
template <bool SWAP>
__device__ __forceinline__ void gemm_core(const bf16_t* __restrict__ A,
                                          const bf16_t* __restrict__ B,
                                          bf16_t* aT, bf16_t* bT,
                                          f32x4 acc[4][4])
{
    const int t = threadIdx.x, w = t >> 6, lane = t & 63;
    const int lid = lane & 15, quad = lane >> 4;
    const int wm = w >> 1, wn = w & 1;
    const int l4 = lane >> 2, k4 = lane & 3;

    for (int kt = 0; kt < 16; ++kt) {
        const int k0 = kt * 32;
        __syncthreads();
#pragma unroll
        for (int i = 0; i < 2; ++i) {
            int q = w * 2 + i;                       // chunk 0..7 (16 rows each)
            int row = q * 16 + l4;
            int kk = k4 ^ ((row >> 1) & 3);
            gload16(A + (size_t)row * CH + k0 + kk * 8, aT + q * 512);
            gload16(B + (size_t)row * CH + k0 + kk * 8, bT + q * 512);
        }
        __syncthreads();

        const bf16_t* mT = SWAP ? bT : aT;
        const bf16_t* nT = SWAP ? aT : bT;
        bf16x8 mf[4], nf[4];
#pragma unroll
        for (int i = 0; i < 4; ++i) {
            int row = wm * 64 + i * 16 + lid;
            int kw = quad ^ ((row >> 1) & 3);
            mf[i] = *(const bf16x8*)(mT + row * 32 + kw * 8);
        }
#pragma unroll
        for (int i = 0; i < 4; ++i) {
            int row = wn * 64 + i * 16 + lid;
            int kw = quad ^ ((row >> 1) & 3);
            nf[i] = *(const bf16x8*)(nT + row * 32 + kw * 8);
        }
#pragma unroll
        for (int mi = 0; mi < 4; ++mi)
#pragma unroll
            for (int ni = 0; ni < 4; ++ni)
                acc[mi][ni] = MFMA16(mf[mi], nf[ni], acc[mi][ni]);
    }
}

// ---------------------------------------------------------------------------
// qkv: grid (160, 8).  bx<32: Q (8 nt x 4 ct); 32..95: K (16 x 4); 96..159: V.
// Q/K write [n][co]; V uses SWAP and writes Vt[co][key] (key-contiguous-ish).
// ---------------------------------------------------------------------------
__global__ __launch_bounds__(256) void qkv_kernel(
    const bf16_t* __restrict__ Xc, const bf16_t* __restrict__ Xn,
    const bf16_t* __restrict__ Wb,
    bf16_t* __restrict__ Qn, bf16_t* __restrict__ Kn, bf16_t* __restrict__ Vt)
{
    __shared__ __align__(16) bf16_t aT[128 * 32];
    __shared__ __align__(16) bf16_t bT[128 * 32];
    const int bx = blockIdx.x, b = blockIdx.y;
    const int t = threadIdx.x, w = t >> 6, lane = t & 63;
    const int lid = lane & 15, quad = lane >> 4;
    const int wm = w >> 1, wn = w & 1;
    const float QSC = 0.125f * 1.44269504f;

    f32x4 acc[4][4] = {};

    if (bx < 96) {                        // Q or K job
        const bf16_t* A; const bf16_t* B; bf16_t* O; float scale;
        if (bx < 32) {
            int nt = bx >> 2, ct = bx & 3;
            A = Xc + (size_t)b * NT * CH + (size_t)nt * 128 * CH;
            B = Wb + (size_t)0 * CH * CH + (size_t)ct * 128 * CH;
            O = Qn + (size_t)b * NT * CH + (size_t)nt * 128 * CH + ct * 128;
            scale = QSC;
        } else {
            int j = bx - 32, nt = j >> 2, ct = j & 3;
            A = Xn + (size_t)b * 2 * NT * CH + (size_t)nt * 128 * CH;
            B = Wb + (size_t)1 * CH * CH + (size_t)ct * 128 * CH;
            O = Kn + (size_t)b * 2 * NT * CH + (size_t)nt * 128 * CH + ct * 128;
            scale = 1.0f;
        }
        gemm_core<false>(A, B, aT, bT, acc);
#pragma unroll
        for (int mi = 0; mi < 4; ++mi)
#pragma unroll
            for (int ni = 0; ni < 4; ++ni)
#pragma unroll
                for (int r = 0; r < 4; ++r) {
                    int n  = wm * 64 + mi * 16 + quad * 4 + r;
                    int co = wn * 64 + ni * 16 + lid;
                    O[(size_t)n * CH + co] = (bf16_t)(acc[mi][ni][r] * scale);
                }
    } else {                              // V job -> Vt[co][key]
        int j = bx - 96, nt = j >> 2, ct = j & 3;
        const bf16_t* A = Xn + (size_t)b * 2 * NT * CH + (size_t)nt * 128 * CH;
        const bf16_t* B = Wb + (size_t)2 * CH * CH + (size_t)ct * 128 * CH;
        bf16_t* O = Vt + (size_t)b * CH * 2 * NT + (size_t)ct * 128 * 2 * NT + nt * 128;
        gemm_core<true>(A, B, aT, bT, acc);
#pragma unroll
        for (int mi = 0; mi < 4; ++mi)
#pragma unroll
            for (int ni = 0; ni < 4; ++ni)
#pragma unroll
                for (int r = 0; r < 4; ++r) {
                    int co_l  = wm * 64 + mi * 16 + quad * 4 + r;
                    int key_l = wn * 64 + ni * 16 + lid;
                    O[(size_t)co_l * (2 * NT) + key_l] = (bf16_t)acc[mi][ni][r];
                }
    }
}

// ---------------------------------------------------------------------------
// attn (unchanged from round 2): S^T formulation, 32x32x16 MFMA, no-max softmax
// ---------------------------------------------------------------------------
__global__ __launch_bounds__(256) void attn_kernel(
    const bf16_t* __restrict__ Qn, const bf16_t* __restrict__ Kn,
    const bf16_t* __restrict__ Vt, bf16_t* __restrict__ AOn)
{
    __shared__ __align__(16) bf16_t kv[128 * 72];
    __shared__ __align__(16) float  pqf[9216];
    __shared__ float l_scr[128];

    bf16_t* pq = (bf16_t*)pqf;

    const int t = threadIdx.x;
    const int w = t >> 6, lane = t & 63;
    const int wq = w >> 1, wk = w & 1;
    const int l31 = lane & 31, h = lane >> 5;

    const int q0 = blockIdx.x * 128;
    const int hh = blockIdx.y, b = blockIdx.z;

    const bf16_t* Qb  = Qn + ((size_t)b * NT + q0) * CH + hh * HD;
    const bf16_t* Kb  = Kn + (size_t)b * 2 * NT * CH + hh * HD;
    const bf16_t* Vtb = Vt + ((size_t)b * CH + hh * HD) * (2 * NT);
    bf16_t* AOb = AOn + ((size_t)b * NT + q0) * CH + hh * HD;

#pragma unroll
    for (int i = 0; i < 4; ++i) {
        int gid = t + i * 256;
        int qr = gid >> 3, c8 = (gid & 7) * 8;
        *(bf16x8*)(pq + qr * 72 + (c8 ^ (qr & 24))) =
            *(const bf16x8*)(Qb + (size_t)qr * CH + c8);
    }
    __syncthreads();

    bf16x8 kreg[4];
#pragma unroll
    for (int i = 0; i < 4; ++i) {
        int gid = t + i * 256;
        int kr = gid >> 3, c8 = (gid & 7) * 8;
        kreg[i] = *(const bf16x8*)(Kb + (size_t)kr * CH + c8);
    }

    bf16x8 qf[2][4];
#pragma unroll
    for (int nf = 0; nf < 2; ++nf)
#pragma unroll
        for (int ks = 0; ks < 4; ++ks) {
            int row = wq * 64 + nf * 32 + l31;
            int col = (ks * 16 + h * 8) ^ (row & 24);
            qf[nf][ks] = *(const bf16x8*)(pq + row * 72 + col);
        }
    __syncthreads();

    bf16_t* pw = pq + w * 4608;

    f32x16 o[2][2] = {};
    float lpart[2] = {0.f, 0.f};

    for (int kt = 0; kt < 16; ++kt) {
        const int kbase = kt * 128;

#pragma unroll
        for (int i = 0; i < 4; ++i) {
            int gid = t + i * 256;
            int kr = gid >> 3, c8 = (gid & 7) * 8;
            *(bf16x8*)(kv + kr * 72 + (c8 ^ (kr & 24))) = kreg[i];
        }
        __syncthreads();

        bf16x8 vreg[4];
#pragma unroll
        for (int i = 0; i < 4; ++i) {
            int gid = t + i * 256;
            int dr = gid >> 4, c8 = (gid & 15) * 8;
            vreg[i] = *(const bf16x8*)(Vtb + (size_t)dr * (2 * NT) + kbase + c8);
        }

        f32x16 s[2][2] = {};
#pragma unroll
        for (int ks = 0; ks < 4; ++ks) {
            bf16x8 af[2];
#pragma unroll
            for (int mf = 0; mf < 2; ++mf) {
                int arow = wk * 64 + mf * 32 + l31;
                int acol = (ks * 16 + h * 8) ^ (arow & 24);
                af[mf] = *(const bf16x8*)(kv + arow * 72 + acol);
            }
#pragma unroll
            for (int mf = 0; mf < 2; ++mf)
#pragma unroll
                for (int nf = 0; nf < 2; ++nf)
                    s[mf][nf] = MFMA32(af[mf], qf[nf][ks], s[mf][nf]);
        }

#pragma unroll
        for (int mf = 0; mf < 2; ++mf)
#pragma unroll
            for (int nf = 0; nf < 2; ++nf) {
                int qrow = nf * 32 + l31;
#pragma unroll
                for (int g = 0; g < 4; ++g) {
                    float p0 = exp2f(s[mf][nf][4 * g + 0]);
                    float p1 = exp2f(s[mf][nf][4 * g + 1]);
                    float p2 = exp2f(s[mf][nf][4 * g + 2]);
                    float p3 = exp2f(s[mf][nf][4 * g + 3]);
                    lpart[nf] += (p0 + p1) + (p2 + p3);
                    bf16x4 pk = { (bf16_t)p0, (bf16_t)p1, (bf16_t)p2, (bf16_t)p3 };
                    int kb = mf * 32 + 8 * g + 4 * h;
                    *(bf16x4*)(pw + qrow * 72 + (kb ^ (qrow & 24))) = pk;
                }
            }
        __syncthreads();

#pragma unroll
        for (int i = 0; i < 4; ++i) {
            int gid = t + i * 256;
            int dr = gid >> 4, c8 = (gid & 15) * 8;
            *(bf16x8*)(kv + dr * 136 + (c8 ^ (dr & 24))) = vreg[i];
        }
        __syncthreads();

        const int nb2 = (kt < 15) ? kbase + 128 : kbase;
#pragma unroll
        for (int i = 0; i < 4; ++i) {
            int gid = t + i * 256;
            int kr = gid >> 3, c8 = (gid & 7) * 8;
            kreg[i] = *(const bf16x8*)(Kb + (size_t)(nb2 + kr) * CH + c8);
        }

#pragma unroll
        for (int ks = 0; ks < 4; ++ks) {
            bf16x8 av[2], bp[2];
#pragma unroll
            for (int df = 0; df < 2; ++df) {
                int vrow = df * 32 + l31;
                int vcol = (wk * 64 + ks * 16 + h * 8) ^ (vrow & 24);
                av[df] = *(const bf16x8*)(kv + vrow * 136 + vcol);
            }
#pragma unroll
            for (int nf = 0; nf < 2; ++nf) {
                int bq = nf * 32 + l31;
                int bcol = (ks * 16 + h * 8) ^ (bq & 24);
                bp[nf] = *(const bf16x8*)(pw + bq * 72 + bcol);
            }
#pragma unroll
            for (int df = 0; df < 2; ++df)
#pragma unroll
                for (int nf = 0; nf < 2; ++nf)
                    o[df][nf] = MFMA32(av[df], bp[nf], o[df][nf]);
        }
        __syncthreads();
    }

    float l2[2];
#pragma unroll
    for (int nf = 0; nf < 2; ++nf)
        l2[nf] = lpart[nf] + __shfl_xor(lpart[nf], 32);

    if (wk == 1) {
        float* scr = pqf + wq * 4352;
#pragma unroll
        for (int df = 0; df < 2; ++df)
#pragma unroll
            for (int nf = 0; nf < 2; ++nf) {
                int qrow = nf * 32 + l31;
#pragma unroll
                for (int g = 0; g < 4; ++g) {
                    int d = df * 32 + 8 * g + 4 * h;
                    f32x4 v = { o[df][nf][4 * g + 0], o[df][nf][4 * g + 1],
                                o[df][nf][4 * g + 2], o[df][nf][4 * g + 3] };
                    *(f32x4*)(scr + qrow * 68 + d) = v;
                }
            }
        if (h == 0) {
            l_scr[wq * 64 + 0 * 32 + l31] = l2[0];
            l_scr[wq * 64 + 1 * 32 + l31] = l2[1];
        }
    }
    __syncthreads();

    if (wk == 0) {
        const float* scr = pqf + wq * 4352;
        float inv[2];
#pragma unroll
        for (int nf = 0; nf < 2; ++nf)
            inv[nf] = 1.0f / (l2[nf] + l_scr[wq * 64 + nf * 32 + l31]);
#pragma unroll
        for (int df = 0; df < 2; ++df)
#pragma unroll
            for (int nf = 0; nf < 2; ++nf) {
                int qrow = nf * 32 + l31;
#pragma unroll
                for (int g = 0; g < 4; ++g) {
                    int d = df * 32 + 8 * g + 4 * h;
                    f32x4 part = *(const f32x4*)(scr + qrow * 68 + d);
                    bf16x4 ov = {
                        (bf16_t)((o[df][nf][4 * g + 0] + part.x) * inv[nf]),
                        (bf16_t)((o[df][nf][4 * g + 1] + part.y) * inv[nf]),
                        (bf16_t)((o[df][nf][4 * g + 2] + part.z) * inv[nf]),
                        (bf16_t)((o[df][nf][4 * g + 3] + part.w) * inv[nf]) };
                    int qg = wq * 64 + qrow;
                    *(bf16x4*)(kv + qg * 72 + (d ^ (qg & 24))) = ov;
                }
            }
    }
    __syncthreads();

#pragma unroll
    for (int i = 0; i < 4; ++i) {
        int gid = t + i * 256;
        int qr = gid >> 3, c8 = (gid & 7) * 8;
        *(bf16x8*)(AOb + (size_t)qr * CH + c8) =
            *(const bf16x8*)(kv + qr * 72 + (c8 ^ (qr & 24)));
    }
}

// ---------------------------------------------------------------------------
// proj: Z^T[b][co][n] = (AO @ Wo^T)^T + f_curr[b][co][n]  (fp32). grid (32, 8)
// SWAP core: m-side = Wo rows (co), n-side = AO rows (n) -> n-coalesced writes
// ---------------------------------------------------------------------------
__global__ __launch_bounds__(256) void proj_kernel(
    const bf16_t* __restrict__ AOn, const bf16_t* __restrict__ Wb,
    const float* __restrict__ fc, float* __restrict__ Zt)
{
    __shared__ __align__(16) bf16_t aT[128 * 32];
    __shared__ __align__(16) bf16_t bT[128 * 32];
    const int bx = blockIdx.x, b = blockIdx.y;
    const int nt = bx >> 2, ct = bx & 3;
    const int t = threadIdx.x, w = t >> 6, lane = t & 63;
    const int lid = lane & 15, quad = lane >> 4;
    const int wm = w >> 1, wn = w & 1;

    const bf16_t* A = AOn + (size_t)b * NT * CH + (size_t)nt * 128 * CH;
    const bf16_t* B = Wb + (size_t)3 * CH * CH + (size_t)ct * 128 * CH;   // Wo

    f32x4 acc[4][4] = {};
    gemm_core<true>(A, B, aT, bT, acc);

    const size_t bofs = (size_t)b * CH * NT;
#pragma unroll
    for (int mi = 0; mi < 4; ++mi)
#pragma unroll
        for (int ni = 0; ni < 4; ++ni)
#pragma unroll
            for (int r = 0; r < 4; ++r) {
                int co_l = wm * 64 + mi * 16 + quad * 4 + r;
                int n_l  = wn * 64 + ni * 16 + lid;
                size_t idx = bofs + (size_t)(ct * 128 + co_l) * NT + nt * 128 + n_l;
                Zt[idx] = acc[mi][ni][r] + fc[idx];
            }
}

// ---------------------------------------------------------------------------
// stats: per (b, n) mean/rsqrt over co of Z^T.  grid (16, 8), block 256.
// ---------------------------------------------------------------------------
__global__ __launch_bounds__(256) void stats_kernel(
    const float* __restrict__ Zt, float* __restrict__ mu_buf,
    float* __restrict__ rs_buf)
{
    __shared__ float sS[1024], sQ[1024];
    const int b = blockIdx.y, n0 = blockIdx.x * 64;
    const int t = threadIdx.x, w = t >> 6, lane = t & 63;
    const int co_off = lane >> 4, n4 = lane & 15;
    const float* Zb = Zt + (size_t)b * CH * NT + n0 + n4 * 4;

    f32x4 s = {0, 0, 0, 0}, q = {0, 0, 0, 0};
    for (int it = 0; it < 32; ++it) {
        int co = w * 4 + co_off + it * 16;
        f32x4 z = *(const f32x4*)(Zb + (size_t)co * NT);
#pragma unroll
        for (int c = 0; c < 4; ++c) { s[c] += z[c]; q[c] += z[c] * z[c]; }
    }
#pragma unroll
    for (int c = 0; c < 4; ++c) { sS[t * 4 + c] = s[c]; sQ[t * 4 + c] = q[c]; }
    __syncthreads();

    if (t < 64) {
        int n4r = t >> 2, comp = t & 3;
        float ss = 0.f, qq = 0.f;
#pragma unroll
        for (int i = 0; i < 16; ++i) {
            int idx = ((i >> 2) * 64 + (i & 3) * 16 + n4r) * 4 + comp;
            ss += sS[idx]; qq += sQ[idx];
        }
        float mu  = ss * (1.0f / 512.0f);
        float var = qq * (1.0f / 512.0f) - mu * mu;
        mu_buf[(size_t)b * NT + n0 + t] = mu;
        rs_buf[(size_t)b * NT + n0 + t] = rsqrtf(var + 1e-5f);
    }
}

// ---------------------------------------------------------------------------
// apply: out[b][co][n] = (z - mu[n]) * rs[n] * gamma[co] + beta[co].
// grid 4096: one block per (b, co) row of 1024 n.
// ---------------------------------------------------------------------------
__global__ __launch_bounds__(256) void apply_kernel(
    const float* __restrict__ Zt, const float* __restrict__ mu_buf,
    const float* __restrict__ rs_buf, const float* __restrict__ gamma,
    const float* __restrict__ beta, float* __restrict__ out)
{
    const int row = blockIdx.x;           // b*512 + co
    const int co = row & 511, b = row >> 9;
    const int t = threadIdx.x;
    const float g = gamma[co], be = beta[co];
    const size_t base = (size_t)row * NT + t * 4;
    f32x4 z  = *(const f32x4*)(Zt + base);
    f32x4 mu = *(const f32x4*)(mu_buf + (size_t)b * NT + t * 4);
    f32x4 rs = *(const f32x4*)(rs_buf + (size_t)b * NT + t * 4);
    f32x4 o;
#pragma unroll
    for (int c = 0; c < 4; ++c) o[c] = (z[c] - mu[c]) * rs[c] * g + be;
    *(f32x4*)(out + base) = o;
}

// ---------------------------------------------------------------------------
extern "C" void kernel_launch(void* const* d_in, const int* in_sizes, int n_in,
                              void* d_out, int out_size, void* d_ws, size_t ws_size,
                              hipStream_t stream)
{
    (void)in_sizes; (void)n_in; (void)out_size; (void)ws_size;
    const float* fc    = (const float*)d_in[0];
    const float* fp    = (const float*)d_in[1];
    const float* fn    = (const float*)d_in[2];
    const float* Wq    = (const float*)d_in[3];
    const float* Wk    = (const float*)d_in[4];
    const float* Wv    = (const float*)d_in[5];
    const float* Wo    = (const float*)d_in[6];
    const float* gamma = (const float*)d_in[7];
    const float* beta  = (const float*)d_in[8];
    float* out = (float*)d_out;

    char* ws = (char*)d_ws;
    // Layout (66.1 MB):
    //   Xn  [0,        16M)   bf16 [8][2048][512]
    //   Qn  [16M,      24M)
    //   Kn  [24M,      40M)
    //   Xc  [40M,      48M)   (AOn overlays Xc: Xc dead after qkv)
    //   Vt  [48M,      64M)
    //   Wb  [64M,      66M)   bf16 Wq|Wk|Wv|Wo
    //   mu  [66M,      +32K)  rs [+32K, +64K)
    //   Zt  [0,        16M)   fp32, overlays Xn (dead after qkv; proj after attn)
    bf16_t* Xn  = (bf16_t*)(ws);
    bf16_t* Qn  = (bf16_t*)(ws + 16777216);
    bf16_t* Kn  = (bf16_t*)(ws + 25165824);
    bf16_t* Xc  = (bf16_t*)(ws + 41943040);
    bf16_t* AOn = Xc;
    bf16_t* Vt  = (bf16_t*)(ws + 50331648);
    bf16_t* Wb  = (bf16_t*)(ws + 67108864);
    float*  mu  = (float*)(ws + 69206016);
    float*  rs  = (float*)(ws + 69238784);
    float*  Zt  = (float*)(ws);

    prep_kernel<<<dim3(128, 24), 256, 0, stream>>>(fc, fp, fn, Xc, Xn);
    wcvt_kernel<<<dim3(256, 4), 256, 0, stream>>>(Wq, Wk, Wv, Wo, Wb);
    qkv_kernel<<<dim3(160, 8), 256, 0, stream>>>(Xc, Xn, Wb, Qn, Kn, Vt);
    attn_kernel<<<dim3(8, 8, 8), 256, 0, stream>>>(Qn, Kn, Vt, AOn);
    proj_kernel<<<dim3(32, 8), 256, 0, stream>>>(AOn, Wb, fc, Zt);
    stats_kernel<<<dim3(16, 8), 256, 0, stream>>>(Zt, mu, rs);
    apply_kernel<<<4096, 256, 0, stream>>>(Zt, mu, rs, gamma, beta, out);
}